// Round 7
// baseline (250.826 us; speedup 1.0000x reference)
//
#include <hip/hip_runtime.h>

typedef unsigned short u16;
typedef unsigned int u32;
typedef __attribute__((ext_vector_type(8))) short short8;
typedef __attribute__((ext_vector_type(4))) float f32x4;
typedef __attribute__((ext_vector_type(4))) u16 u16x4;

__device__ __forceinline__ u16 f2bf(float f) {
  union { float f; unsigned u; } x; x.f = f;
  unsigned r = (x.u + 0x7fffu + ((x.u >> 16) & 1u)) >> 16;
  return (u16)r;
}

__device__ __forceinline__ u16 f2bf_rna(float f) {
  union { float f; u32 u; } x; x.f = f;
  return (u16)((x.u + 0x8000u) >> 16);
}

__device__ __forceinline__ f32x4 mfma16(short8 a, short8 b, f32x4 c) {
  return __builtin_amdgcn_mfma_f32_16x16x32_bf16(a, b, c, 0, 0, 0);
}

__device__ __forceinline__ void gload16(const u16* g, u16* l) {
  __builtin_amdgcn_global_load_lds((const __attribute__((address_space(1))) void*)g,
                                   (__attribute__((address_space(3))) void*)l, 16, 0, 0);
}

// Fused prep: w_attn^T cast (0..1151), w_proj^T cast (1152..2175), x->bf16 (2176..4223).
__global__ __launch_bounds__(256) void prep(const float* __restrict__ x,
                                            const float* __restrict__ w_attn,
                                            const float* __restrict__ w_proj,
                                            u16* __restrict__ xb,
                                            u16* __restrict__ wat,
                                            u16* __restrict__ wpt) {
  __shared__ float tile[32][33];
  const int bid = blockIdx.x, tid = threadIdx.x;
  if (bid >= 2176) {
    const int id = bid - 2176;
    const f32x4* src = (const f32x4*)(x + (size_t)id * 4096);
    u16x4* dst = (u16x4*)(xb + (size_t)id * 4096);
#pragma unroll
    for (int c = 0; c < 4; ++c) {
      f32x4 v = src[c * 256 + tid];
      u16x4 o;
#pragma unroll
      for (int j = 0; j < 4; ++j) o[j] = f2bf(v[j]);
      dst[c * 256 + tid] = o;
    }
    return;
  }
  const float* src; u16* dst; int C, bx, by;
  if (bid < 1152) { src = w_attn; dst = wat; C = 1152; bx = bid % 36; by = bid / 36; }
  else { int id = bid - 1152; src = w_proj; dst = wpt; C = 1024; bx = id & 31; by = id >> 5; }
  const int R = 1024;
  const int tx = tid & 31, ty = tid >> 5;
  int c = bx * 32 + tx, r0 = by * 32;
#pragma unroll
  for (int i = 0; i < 32; i += 8)
    tile[ty + i][tx] = src[(size_t)(r0 + ty + i) * C + c];
  __syncthreads();
  int oc = r0 + tx, orow0 = bx * 32;
#pragma unroll
  for (int i = 0; i < 32; i += 8)
    dst[(size_t)(orow0 + ty + i) * R + oc] = f2bf(tile[tx][ty + i]);
}

// C[m][n] = sum_k A[m][k] * Bt[n][k].  128x128 tile, BK=32, 4 waves, both bf16.
// Single-barrier double-buffered K-loop: prefetch tile t+1 (global_load_lds)
// into buf^1 before computing tile t from buf; one __syncthreads per iter.
template <bool C_F32, bool VT>
__global__ __launch_bounds__(256) void gemm_bt(const u16* __restrict__ A,
                                               const u16* __restrict__ Bt,
                                               void* __restrict__ Cp,
                                               u16* __restrict__ vt,
                                               int lda, int ldb, int ldc, int K) {
  __shared__ u16 As[2][128 * 32];
  __shared__ u16 Bs[2][128 * 32];
  const int tid = threadIdx.x;
  const int wid = tid >> 6, lane = tid & 63;
  const int quad = lane >> 4, l15 = lane & 15;
  const int m0 = blockIdx.y * 128, n0 = blockIdx.x * 128;
  const int wm = (wid & 1) * 64, wn = (wid >> 1) * 64;
  const int sr = tid >> 2;
  const int sc = (tid & 3) * 8;

  f32x4 acc[4][4] = {};

  auto stage = [&](int t, int bb) {
    const int k0 = t << 5;
#pragma unroll
    for (int cch = 0; cch < 2; ++cch) {
      const int row = sr + cch * 64;
      gload16(A + (size_t)(m0 + row) * lda + k0 + sc, &As[bb][wid * 512 + cch * 2048]);
      gload16(Bt + (size_t)(n0 + row) * ldb + k0 + sc, &Bs[bb][wid * 512 + cch * 2048]);
    }
  };

  const int nk = K >> 5;
  stage(0, 0);
  for (int t = 0; t < nk; ++t) {
    const int bb = t & 1;
    __syncthreads();  // drains prefetch into bb (vmcnt) + prior reads (lgkm)
    if (t + 1 < nk) stage(t + 1, bb ^ 1);
    short8 a[4], b[4];
#pragma unroll
    for (int i = 0; i < 4; ++i) a[i] = *(const short8*)&As[bb][(wm + 16 * i + l15) * 32 + quad * 8];
#pragma unroll
    for (int j = 0; j < 4; ++j) b[j] = *(const short8*)&Bs[bb][(wn + 16 * j + l15) * 32 + quad * 8];
#pragma unroll
    for (int i = 0; i < 4; ++i)
#pragma unroll
      for (int j = 0; j < 4; ++j)
        acc[i][j] = mfma16(a[i], b[j], acc[i][j]);
  }

#pragma unroll
  for (int i = 0; i < 4; ++i) {
#pragma unroll
    for (int j = 0; j < 4; ++j) {
      const int mrow = m0 + wm + 16 * i + quad * 4;
      const int ncol = n0 + wn + 16 * j + l15;
#pragma unroll
      for (int r = 0; r < 4; ++r) {
        float v = acc[i][j][r];
        if (C_F32) {
          ((float*)Cp)[(size_t)(mrow + r) * ldc + ncol] = v;
        } else {
          u16 hv = f2bf(v);
          ((u16*)Cp)[(size_t)(mrow + r) * ldc + ncol] = hv;
          if (VT) {
            if (ncol >= 1088) {
              int mg = mrow + r;
              int bb2 = mg >> 11, tt = mg & 2047;
              vt[(size_t)(bb2 * 64 + (ncol - 1088)) * 2048 + tt] = hv;
            }
          }
        }
      }
    }
  }
}

// Flash causal MQA, S^T form, fixed-shift softmax, MFMA row-sum (ones trick).
// grid 1024, qt-descending. LDS 25.5KB (stride-68 tiles, single shared Pw with
// serialized jt PV) -> up to 6 blocks/CU. No min-waves bound (spill lesson, R3).
__global__ __launch_bounds__(256) void attn_kernel(const u16* __restrict__ qkv,
                                                   const u16* __restrict__ vt,
                                                   u16* __restrict__ y) {
  const int T = 2048, LD = 1152;
  __shared__ u16 Ks[64 * 68];      // [kv][d]
  __shared__ u16 Vts[64 * 68];     // [d][kv]
  __shared__ u16 Pw[4][16 * 68];   // per-wave P^T, shared across jt

  const int bid = blockIdx.x;
  const int qt = 15 - (bid >> 6);  // descending: long blocks launch first
  const int bh = bid & 63, b = bh >> 4, h = bh & 15;
  const int q0 = qt * 128;
  const int tid = threadIdx.x, wid = tid >> 6, lane = tid & 63;
  const int quad = lane >> 4, l15 = lane & 15;
  const int wq = wid * 32;
  const u16* qkvb = qkv + (size_t)b * T * LD;
  const u16* vtb = vt + (size_t)b * 64 * 2048;
  const int sr0 = tid >> 3, sc0 = (tid & 7) * 8;
  const int sr1 = sr0 + 32;
  const float c1 = 0.18033688f;  // 0.125 * log2(e)
  const float M = 18.0f;         // fixed softmax shift
  short8 ones;
#pragma unroll
  for (int j = 0; j < 8; ++j) ones[j] = (short)0x3F80;  // bf16 1.0

  short8 qreg[2][2];
#pragma unroll
  for (int jt = 0; jt < 2; ++jt)
#pragma unroll
    for (int ks = 0; ks < 2; ++ks)
      qreg[jt][ks] = *(const short8*)(qkvb + (size_t)(q0 + wq + 16 * jt + l15) * LD + h * 64 + ks * 32 + quad * 8);

  f32x4 acc[4][2] = {};
  f32x4 accs[2] = {};   // row-sums via ones-MFMA

  short8 kr0 = *(const short8*)(qkvb + (size_t)sr0 * LD + 1024 + sc0);
  short8 kr1 = *(const short8*)(qkvb + (size_t)sr1 * LD + 1024 + sc0);
  short8 vr0 = *(const short8*)(vtb + (size_t)sr0 * 2048 + sc0);
  short8 vr1 = *(const short8*)(vtb + (size_t)sr1 * 2048 + sc0);

  const int ktmax = 2 * qt + 2;
  for (int kt = 0; kt < ktmax; ++kt) {
    const int kv0 = kt * 64;
    __syncthreads();
    *(short8*)&Ks[sr0 * 68 + sc0] = kr0;
    *(short8*)&Ks[sr1 * 68 + sc0] = kr1;
    *(short8*)&Vts[sr0 * 68 + sc0] = vr0;
    *(short8*)&Vts[sr1 * 68 + sc0] = vr1;
    __syncthreads();
    if (kt + 1 < ktmax) {
      const int nv0 = kv0 + 64;
      kr0 = *(const short8*)(qkvb + (size_t)(nv0 + sr0) * LD + 1024 + sc0);
      kr1 = *(const short8*)(qkvb + (size_t)(nv0 + sr1) * LD + 1024 + sc0);
      vr0 = *(const short8*)(vtb + (size_t)sr0 * 2048 + nv0 + sc0);
      vr1 = *(const short8*)(vtb + (size_t)sr1 * 2048 + nv0 + sc0);
    }
    if (kv0 > q0 + wq + 31) continue;  // fully masked for this wave

    // S^T = K * Q^T (kf shared across jt)
    f32x4 st[4][2] = {};
#pragma unroll
    for (int ks = 0; ks < 2; ++ks) {
      short8 kf[4];
#pragma unroll
      for (int i = 0; i < 4; ++i) kf[i] = *(const short8*)&Ks[(16 * i + l15) * 68 + ks * 32 + quad * 8];
#pragma unroll
      for (int i = 0; i < 4; ++i)
#pragma unroll
        for (int jt = 0; jt < 2; ++jt)
          st[i][jt] = mfma16(kf[i], qreg[jt][ks], st[i][jt]);
    }

    // serialized per-jt: softmax -> Pw (shared buffer) -> PV
    const bool needMask = (kv0 + 63 > q0 + wq);
    u16* pw = Pw[wid];
#pragma unroll
    for (int jt = 0; jt < 2; ++jt) {
      const int qg = q0 + wq + 16 * jt + l15;
#pragma unroll
      for (int i = 0; i < 4; ++i) {
        u16x4 pk;
#pragma unroll
        for (int r = 0; r < 4; ++r) {
          float p = __builtin_amdgcn_exp2f(fmaf(st[i][jt][r], c1, -M));
          if (needMask && (kv0 + 16 * i + quad * 4 + r > qg)) p = 0.f;
          pk[r] = f2bf_rna(p);
        }
        *(u16x4*)&pw[l15 * 68 + 16 * i + quad * 4] = pk;
      }
      // O^T += V^T * P^T ; row-sum += ones * P^T (wave-local, no barrier)
#pragma unroll
      for (int ks = 0; ks < 2; ++ks) {
        short8 pf = *(const short8*)&pw[l15 * 68 + ks * 32 + quad * 8];
#pragma unroll
        for (int id = 0; id < 4; ++id) {
          short8 vf = *(const short8*)&Vts[(16 * id + l15) * 68 + ks * 32 + quad * 8];
          acc[id][jt] = mfma16(vf, pf, acc[id][jt]);
        }
        accs[jt] = mfma16(ones, pf, accs[jt]);
      }
    }
  }

  // epilogue: every element of accs[jt] equals this q-col's row-sum
#pragma unroll
  for (int jt = 0; jt < 2; ++jt) {
    const float inv = 1.f / accs[jt][0];
    const int qg = q0 + wq + 16 * jt + l15;
#pragma unroll
    for (int id = 0; id < 4; ++id) {
      u16x4 o;
#pragma unroll
      for (int r = 0; r < 4; ++r) o[r] = f2bf(acc[id][jt][r] * inv);
      *(u16x4*)(y + (size_t)(b * T + qg) * 1024 + h * 64 + 16 * id + quad * 4) = o;
    }
  }
}

extern "C" void kernel_launch(void* const* d_in, const int* in_sizes, int n_in,
                              void* d_out, int out_size, void* d_ws, size_t ws_size,
                              hipStream_t stream) {
  const float* x = (const float*)d_in[0];       // (4,2048,1024)
  const float* w_attn = (const float*)d_in[1];  // (1024,1152)
  const float* w_proj = (const float*)d_in[2];  // (1024,1024)
  float* out = (float*)d_out;                   // (4,2048,1024) fp32
  char* ws = (char*)d_ws;

  u16* wat = (u16*)ws;                       // 1152x1024 bf16
  u16* wpt = (u16*)(ws + 2359296);           // 1024x1024 bf16
  u16* xb  = (u16*)(ws + 4456448);           // 8192x1024 bf16
  u16* qkv = (u16*)(ws + 21233664);          // 8192x1152 bf16
  u16* vt  = (u16*)(ws + 40108032);          // 4x64x2048 bf16
  u16* y   = (u16*)(ws + 41156608);          // 8192x1024 bf16

  prep<<<dim3(4224), dim3(256), 0, stream>>>(x, w_attn, w_proj, xb, wat, wpt);
  gemm_bt<false, true><<<dim3(9, 64), 256, 0, stream>>>(xb, wat, qkv, vt, 1024, 1024, 1152, 1024);
  attn_kernel<<<dim3(1024), dim3(256), 0, stream>>>(qkv, vt, y);
  gemm_bt<true, false><<<dim3(8, 64), 256, 0, stream>>>(y, wpt, out, nullptr, 1024, 1024, 1024, 1024);
}

// Round 8
// 216.343 us; speedup vs baseline: 1.1594x; 1.1594x over previous
//
#include <hip/hip_runtime.h>

typedef unsigned short u16;
typedef unsigned int u32;
typedef __attribute__((ext_vector_type(8))) short short8;
typedef __attribute__((ext_vector_type(4))) float f32x4;
typedef __attribute__((ext_vector_type(4))) u16 u16x4;

__device__ __forceinline__ u16 f2bf(float f) {
  union { float f; unsigned u; } x; x.f = f;
  unsigned r = (x.u + 0x7fffu + ((x.u >> 16) & 1u)) >> 16;
  return (u16)r;
}

__device__ __forceinline__ u16 f2bf_rna(float f) {
  union { float f; u32 u; } x; x.f = f;
  return (u16)((x.u + 0x8000u) >> 16);
}

__device__ __forceinline__ f32x4 mfma16(short8 a, short8 b, f32x4 c) {
  return __builtin_amdgcn_mfma_f32_16x16x32_bf16(a, b, c, 0, 0, 0);
}

__device__ __forceinline__ void gload16(const u16* g, u16* l) {
  __builtin_amdgcn_global_load_lds((const __attribute__((address_space(1))) void*)g,
                                   (__attribute__((address_space(3))) void*)l, 16, 0, 0);
}

// Fused prep: w_attn^T cast (0..1151), w_proj^T cast (1152..2175), x->bf16 (2176..4223).
__global__ __launch_bounds__(256) void prep(const float* __restrict__ x,
                                            const float* __restrict__ w_attn,
                                            const float* __restrict__ w_proj,
                                            u16* __restrict__ xb,
                                            u16* __restrict__ wat,
                                            u16* __restrict__ wpt) {
  __shared__ float tile[32][33];
  const int bid = blockIdx.x, tid = threadIdx.x;
  if (bid >= 2176) {
    const int id = bid - 2176;
    const f32x4* src = (const f32x4*)(x + (size_t)id * 4096);
    u16x4* dst = (u16x4*)(xb + (size_t)id * 4096);
#pragma unroll
    for (int c = 0; c < 4; ++c) {
      f32x4 v = src[c * 256 + tid];
      u16x4 o;
#pragma unroll
      for (int j = 0; j < 4; ++j) o[j] = f2bf(v[j]);
      dst[c * 256 + tid] = o;
    }
    return;
  }
  const float* src; u16* dst; int C, bx, by;
  if (bid < 1152) { src = w_attn; dst = wat; C = 1152; bx = bid % 36; by = bid / 36; }
  else { int id = bid - 1152; src = w_proj; dst = wpt; C = 1024; bx = id & 31; by = id >> 5; }
  const int R = 1024;
  const int tx = tid & 31, ty = tid >> 5;
  int c = bx * 32 + tx, r0 = by * 32;
#pragma unroll
  for (int i = 0; i < 32; i += 8)
    tile[ty + i][tx] = src[(size_t)(r0 + ty + i) * C + c];
  __syncthreads();
  int oc = r0 + tx, orow0 = bx * 32;
#pragma unroll
  for (int i = 0; i < 32; i += 8)
    dst[(size_t)(orow0 + ty + i) * R + oc] = f2bf(tile[tx][ty + i]);
}

// C[m][n] = sum_k A[m][k] * Bt[n][k].  128x128 tile, BK=32, 4 waves, both bf16.
// Single-barrier double-buffered K-loop (prefetch t+1 into buf^1 during compute of t).
template <bool C_F32, bool VT>
__global__ __launch_bounds__(256) void gemm_bt(const u16* __restrict__ A,
                                               const u16* __restrict__ Bt,
                                               void* __restrict__ Cp,
                                               u16* __restrict__ vt,
                                               int lda, int ldb, int ldc, int K) {
  __shared__ u16 As[2][128 * 32];
  __shared__ u16 Bs[2][128 * 32];
  const int tid = threadIdx.x;
  const int wid = tid >> 6, lane = tid & 63;
  const int quad = lane >> 4, l15 = lane & 15;
  const int m0 = blockIdx.y * 128, n0 = blockIdx.x * 128;
  const int wm = (wid & 1) * 64, wn = (wid >> 1) * 64;
  const int sr = tid >> 2;
  const int sc = (tid & 3) * 8;

  f32x4 acc[4][4] = {};

  auto stage = [&](int t, int bb) {
    const int k0 = t << 5;
#pragma unroll
    for (int cch = 0; cch < 2; ++cch) {
      const int row = sr + cch * 64;
      gload16(A + (size_t)(m0 + row) * lda + k0 + sc, &As[bb][wid * 512 + cch * 2048]);
      gload16(Bt + (size_t)(n0 + row) * ldb + k0 + sc, &Bs[bb][wid * 512 + cch * 2048]);
    }
  };

  const int nk = K >> 5;
  stage(0, 0);
  for (int t = 0; t < nk; ++t) {
    const int bb = t & 1;
    __syncthreads();
    if (t + 1 < nk) stage(t + 1, bb ^ 1);
    short8 a[4], b[4];
#pragma unroll
    for (int i = 0; i < 4; ++i) a[i] = *(const short8*)&As[bb][(wm + 16 * i + l15) * 32 + quad * 8];
#pragma unroll
    for (int j = 0; j < 4; ++j) b[j] = *(const short8*)&Bs[bb][(wn + 16 * j + l15) * 32 + quad * 8];
#pragma unroll
    for (int i = 0; i < 4; ++i)
#pragma unroll
      for (int j = 0; j < 4; ++j)
        acc[i][j] = mfma16(a[i], b[j], acc[i][j]);
  }

#pragma unroll
  for (int i = 0; i < 4; ++i) {
#pragma unroll
    for (int j = 0; j < 4; ++j) {
      const int mrow = m0 + wm + 16 * i + quad * 4;
      const int ncol = n0 + wn + 16 * j + l15;
#pragma unroll
      for (int r = 0; r < 4; ++r) {
        float v = acc[i][j][r];
        if (C_F32) {
          ((float*)Cp)[(size_t)(mrow + r) * ldc + ncol] = v;
        } else {
          u16 hv = f2bf(v);
          ((u16*)Cp)[(size_t)(mrow + r) * ldc + ncol] = hv;
          if (VT) {
            if (ncol >= 1088) {
              int mg = mrow + r;
              int bb2 = mg >> 11, tt = mg & 2047;
              vt[(size_t)(bb2 * 64 + (ncol - 1088)) * 2048 + tt] = hv;
            }
          }
        }
      }
    }
  }
}

// Flash causal MQA, S^T form, fixed-shift softmax, MFMA row-sum (ones trick).
// Round-6 dataflow (dual per-jt Pw, write-all-then-read-all, shared Vts frags)
// + stride-68 padding everywhere (0 bank conflicts). LDS 34KB -> 4 blocks/CU.
__global__ __launch_bounds__(256) void attn_kernel(const u16* __restrict__ qkv,
                                                   const u16* __restrict__ vt,
                                                   u16* __restrict__ y) {
  const int T = 2048, LD = 1152;
  __shared__ u16 Ks[64 * 68];         // [kv][d]
  __shared__ u16 Vts[64 * 68];        // [d][kv]
  __shared__ u16 Pw[4][2][16 * 68];   // per-wave, per-jt P^T: [q 16][kv 64]

  const int bid = blockIdx.x;
  const int qt = 15 - (bid >> 6);     // descending: long blocks launch first
  const int bh = bid & 63, b = bh >> 4, h = bh & 15;
  const int q0 = qt * 128;
  const int tid = threadIdx.x, wid = tid >> 6, lane = tid & 63;
  const int quad = lane >> 4, l15 = lane & 15;
  const int wq = wid * 32;
  const u16* qkvb = qkv + (size_t)b * T * LD;
  const u16* vtb = vt + (size_t)b * 64 * 2048;
  const int sr0 = tid >> 3, sc0 = (tid & 7) * 8;
  const int sr1 = sr0 + 32;
  const float c1 = 0.18033688f;  // 0.125 * log2(e)
  const float M = 18.0f;         // fixed softmax shift
  short8 ones;
#pragma unroll
  for (int j = 0; j < 8; ++j) ones[j] = (short)0x3F80;  // bf16 1.0

  short8 qreg[2][2];
#pragma unroll
  for (int jt = 0; jt < 2; ++jt)
#pragma unroll
    for (int ks = 0; ks < 2; ++ks)
      qreg[jt][ks] = *(const short8*)(qkvb + (size_t)(q0 + wq + 16 * jt + l15) * LD + h * 64 + ks * 32 + quad * 8);

  f32x4 acc[4][2] = {};
  f32x4 accs[2] = {};   // row-sums via ones-MFMA

  short8 kr0 = *(const short8*)(qkvb + (size_t)sr0 * LD + 1024 + sc0);
  short8 kr1 = *(const short8*)(qkvb + (size_t)sr1 * LD + 1024 + sc0);
  short8 vr0 = *(const short8*)(vtb + (size_t)sr0 * 2048 + sc0);
  short8 vr1 = *(const short8*)(vtb + (size_t)sr1 * 2048 + sc0);

  const int ktmax = 2 * qt + 2;
  for (int kt = 0; kt < ktmax; ++kt) {
    const int kv0 = kt * 64;
    __syncthreads();
    *(short8*)&Ks[sr0 * 68 + sc0] = kr0;
    *(short8*)&Ks[sr1 * 68 + sc0] = kr1;
    *(short8*)&Vts[sr0 * 68 + sc0] = vr0;
    *(short8*)&Vts[sr1 * 68 + sc0] = vr1;
    __syncthreads();
    if (kt + 1 < ktmax) {
      const int nv0 = kv0 + 64;
      kr0 = *(const short8*)(qkvb + (size_t)(nv0 + sr0) * LD + 1024 + sc0);
      kr1 = *(const short8*)(qkvb + (size_t)(nv0 + sr1) * LD + 1024 + sc0);
      vr0 = *(const short8*)(vtb + (size_t)sr0 * 2048 + nv0 + sc0);
      vr1 = *(const short8*)(vtb + (size_t)sr1 * 2048 + nv0 + sc0);
    }
    if (kv0 > q0 + wq + 31) continue;  // fully masked for this wave

    // S^T = K * Q^T (kf shared across jt)
    f32x4 st[4][2] = {};
#pragma unroll
    for (int ks = 0; ks < 2; ++ks) {
      short8 kf[4];
#pragma unroll
      for (int i = 0; i < 4; ++i) kf[i] = *(const short8*)&Ks[(16 * i + l15) * 68 + ks * 32 + quad * 8];
#pragma unroll
      for (int i = 0; i < 4; ++i)
#pragma unroll
        for (int jt = 0; jt < 2; ++jt)
          st[i][jt] = mfma16(kf[i], qreg[jt][ks], st[i][jt]);
    }

    // fixed-shift softmax -> both jt P^T tiles written before any Pw read
    const bool needMask = (kv0 + 63 > q0 + wq);
#pragma unroll
    for (int jt = 0; jt < 2; ++jt) {
      u16* pw = &Pw[wid][jt][0];
      const int qg = q0 + wq + 16 * jt + l15;
#pragma unroll
      for (int i = 0; i < 4; ++i) {
        u16x4 pk;
#pragma unroll
        for (int r = 0; r < 4; ++r) {
          float p = __builtin_amdgcn_exp2f(fmaf(st[i][jt][r], c1, -M));
          if (needMask && (kv0 + 16 * i + quad * 4 + r > qg)) p = 0.f;
          pk[r] = f2bf_rna(p);
        }
        *(u16x4*)&pw[l15 * 68 + 16 * i + quad * 4] = pk;
      }
    }

    // O^T += V^T * P^T ; row-sum += ones * P^T (Vts frags shared across jt)
#pragma unroll
    for (int ks = 0; ks < 2; ++ks) {
      short8 pf[2];
#pragma unroll
      for (int jt = 0; jt < 2; ++jt)
        pf[jt] = *(const short8*)&Pw[wid][jt][l15 * 68 + ks * 32 + quad * 8];
#pragma unroll
      for (int id = 0; id < 4; ++id) {
        short8 vf = *(const short8*)&Vts[(16 * id + l15) * 68 + ks * 32 + quad * 8];
        acc[id][0] = mfma16(vf, pf[0], acc[id][0]);
        acc[id][1] = mfma16(vf, pf[1], acc[id][1]);
      }
      accs[0] = mfma16(ones, pf[0], accs[0]);
      accs[1] = mfma16(ones, pf[1], accs[1]);
    }
  }

  // epilogue: every element of accs[jt] equals this q-col's row-sum
#pragma unroll
  for (int jt = 0; jt < 2; ++jt) {
    const float inv = 1.f / accs[jt][0];
    const int qg = q0 + wq + 16 * jt + l15;
#pragma unroll
    for (int id = 0; id < 4; ++id) {
      u16x4 o;
#pragma unroll
      for (int r = 0; r < 4; ++r) o[r] = f2bf(acc[id][jt][r] * inv);
      *(u16x4*)(y + (size_t)(b * T + qg) * 1024 + h * 64 + 16 * id + quad * 4) = o;
    }
  }
}

extern "C" void kernel_launch(void* const* d_in, const int* in_sizes, int n_in,
                              void* d_out, int out_size, void* d_ws, size_t ws_size,
                              hipStream_t stream) {
  const float* x = (const float*)d_in[0];       // (4,2048,1024)
  const float* w_attn = (const float*)d_in[1];  // (1024,1152)
  const float* w_proj = (const float*)d_in[2];  // (1024,1024)
  float* out = (float*)d_out;                   // (4,2048,1024) fp32
  char* ws = (char*)d_ws;

  u16* wat = (u16*)ws;                       // 1152x1024 bf16
  u16* wpt = (u16*)(ws + 2359296);           // 1024x1024 bf16
  u16* xb  = (u16*)(ws + 4456448);           // 8192x1024 bf16
  u16* qkv = (u16*)(ws + 21233664);          // 8192x1152 bf16
  u16* vt  = (u16*)(ws + 40108032);          // 4x64x2048 bf16
  u16* y   = (u16*)(ws + 41156608);          // 8192x1024 bf16

  prep<<<dim3(4224), dim3(256), 0, stream>>>(x, w_attn, w_proj, xb, wat, wpt);
  gemm_bt<false, true><<<dim3(9, 64), 256, 0, stream>>>(xb, wat, qkv, vt, 1024, 1024, 1152, 1024);
  attn_kernel<<<dim3(1024), dim3(256), 0, stream>>>(qkv, vt, y);
  gemm_bt<true, false><<<dim3(8, 64), 256, 0, stream>>>(y, wpt, out, nullptr, 1024, 1024, 1024, 1024);
}

// Round 9
// 208.460 us; speedup vs baseline: 1.2032x; 1.0378x over previous
//
#include <hip/hip_runtime.h>

typedef unsigned short u16;
typedef unsigned int u32;
typedef __attribute__((ext_vector_type(8))) short short8;
typedef __attribute__((ext_vector_type(4))) float f32x4;
typedef __attribute__((ext_vector_type(4))) u16 u16x4;

__device__ __forceinline__ u16 f2bf(float f) {
  union { float f; unsigned u; } x; x.f = f;
  unsigned r = (x.u + 0x7fffu + ((x.u >> 16) & 1u)) >> 16;
  return (u16)r;
}

__device__ __forceinline__ u16 f2bf_rna(float f) {
  union { float f; u32 u; } x; x.f = f;
  return (u16)((x.u + 0x8000u) >> 16);
}

__device__ __forceinline__ f32x4 mfma16(short8 a, short8 b, f32x4 c) {
  return __builtin_amdgcn_mfma_f32_16x16x32_bf16(a, b, c, 0, 0, 0);
}

__device__ __forceinline__ void gload16(const u16* g, u16* l) {
  __builtin_amdgcn_global_load_lds((const __attribute__((address_space(1))) void*)g,
                                   (__attribute__((address_space(3))) void*)l, 16, 0, 0);
}

// Fused prep: w_attn^T cast (0..1151), w_proj^T cast (1152..2175), x->bf16 (2176..4223).
__global__ __launch_bounds__(256) void prep(const float* __restrict__ x,
                                            const float* __restrict__ w_attn,
                                            const float* __restrict__ w_proj,
                                            u16* __restrict__ xb,
                                            u16* __restrict__ wat,
                                            u16* __restrict__ wpt) {
  __shared__ float tile[32][33];
  const int bid = blockIdx.x, tid = threadIdx.x;
  if (bid >= 2176) {
    const int id = bid - 2176;
    const f32x4* src = (const f32x4*)(x + (size_t)id * 4096);
    u16x4* dst = (u16x4*)(xb + (size_t)id * 4096);
#pragma unroll
    for (int c = 0; c < 4; ++c) {
      f32x4 v = src[c * 256 + tid];
      u16x4 o;
#pragma unroll
      for (int j = 0; j < 4; ++j) o[j] = f2bf(v[j]);
      dst[c * 256 + tid] = o;
    }
    return;
  }
  const float* src; u16* dst; int C, bx, by;
  if (bid < 1152) { src = w_attn; dst = wat; C = 1152; bx = bid % 36; by = bid / 36; }
  else { int id = bid - 1152; src = w_proj; dst = wpt; C = 1024; bx = id & 31; by = id >> 5; }
  const int R = 1024;
  const int tx = tid & 31, ty = tid >> 5;
  int c = bx * 32 + tx, r0 = by * 32;
#pragma unroll
  for (int i = 0; i < 32; i += 8)
    tile[ty + i][tx] = src[(size_t)(r0 + ty + i) * C + c];
  __syncthreads();
  int oc = r0 + tx, orow0 = bx * 32;
#pragma unroll
  for (int i = 0; i < 32; i += 8)
    dst[(size_t)(orow0 + ty + i) * R + oc] = f2bf(tile[tx][ty + i]);
}

// C[m][n] = sum_k A[m][k] * Bt[n][k].  128x128 tile, BK=32, 4 waves, both bf16.
// Single-barrier double-buffered K-loop (prefetch t+1 into buf^1 during compute of t).
// Grid is (m, n) with m on blockIdx.x: same-m blocks are 64 apart in linear id
// == same XCD (64 % 8 == 0), so the A-tile row is fetched once into that XCD's
// L2 and all n-blocks hit L2 (~200cyc, fully hidden by the dbuf prefetch gap).
template <bool C_F32, bool VT>
__global__ __launch_bounds__(256) void gemm_bt(const u16* __restrict__ A,
                                               const u16* __restrict__ Bt,
                                               void* __restrict__ Cp,
                                               u16* __restrict__ vt,
                                               int lda, int ldb, int ldc, int K) {
  __shared__ u16 As[2][128 * 32];
  __shared__ u16 Bs[2][128 * 32];
  const int tid = threadIdx.x;
  const int wid = tid >> 6, lane = tid & 63;
  const int quad = lane >> 4, l15 = lane & 15;
  const int m0 = blockIdx.x * 128, n0 = blockIdx.y * 128;   // m-major grid (XCD A-reuse)
  const int wm = (wid & 1) * 64, wn = (wid >> 1) * 64;
  const int sr = tid >> 2;
  const int sc = (tid & 3) * 8;

  f32x4 acc[4][4] = {};

  auto stage = [&](int t, int bb) {
    const int k0 = t << 5;
#pragma unroll
    for (int cch = 0; cch < 2; ++cch) {
      const int row = sr + cch * 64;
      gload16(A + (size_t)(m0 + row) * lda + k0 + sc, &As[bb][wid * 512 + cch * 2048]);
      gload16(Bt + (size_t)(n0 + row) * ldb + k0 + sc, &Bs[bb][wid * 512 + cch * 2048]);
    }
  };

  const int nk = K >> 5;
  stage(0, 0);
  for (int t = 0; t < nk; ++t) {
    const int bb = t & 1;
    __syncthreads();
    if (t + 1 < nk) stage(t + 1, bb ^ 1);
    short8 a[4], b[4];
#pragma unroll
    for (int i = 0; i < 4; ++i) a[i] = *(const short8*)&As[bb][(wm + 16 * i + l15) * 32 + quad * 8];
#pragma unroll
    for (int j = 0; j < 4; ++j) b[j] = *(const short8*)&Bs[bb][(wn + 16 * j + l15) * 32 + quad * 8];
#pragma unroll
    for (int i = 0; i < 4; ++i)
#pragma unroll
      for (int j = 0; j < 4; ++j)
        acc[i][j] = mfma16(a[i], b[j], acc[i][j]);
  }

#pragma unroll
  for (int i = 0; i < 4; ++i) {
#pragma unroll
    for (int j = 0; j < 4; ++j) {
      const int mrow = m0 + wm + 16 * i + quad * 4;
      const int ncol = n0 + wn + 16 * j + l15;
#pragma unroll
      for (int r = 0; r < 4; ++r) {
        float v = acc[i][j][r];
        if (C_F32) {
          ((float*)Cp)[(size_t)(mrow + r) * ldc + ncol] = v;
        } else {
          u16 hv = f2bf(v);
          ((u16*)Cp)[(size_t)(mrow + r) * ldc + ncol] = hv;
          if (VT) {
            if (ncol >= 1088) {
              int mg = mrow + r;
              int bb2 = mg >> 11, tt = mg & 2047;
              vt[(size_t)(bb2 * 64 + (ncol - 1088)) * 2048 + tt] = hv;
            }
          }
        }
      }
    }
  }
}

// Flash causal MQA, S^T form, fixed-shift softmax, MFMA row-sum (ones trick).
// Round-6 dataflow + stride-68 padding (0 bank conflicts). LDS 34KB -> 4 blocks/CU.
// UNCHANGED from round 8 (isolating the GEMM grid-transpose effect).
__global__ __launch_bounds__(256) void attn_kernel(const u16* __restrict__ qkv,
                                                   const u16* __restrict__ vt,
                                                   u16* __restrict__ y) {
  const int T = 2048, LD = 1152;
  __shared__ u16 Ks[64 * 68];         // [kv][d]
  __shared__ u16 Vts[64 * 68];        // [d][kv]
  __shared__ u16 Pw[4][2][16 * 68];   // per-wave, per-jt P^T: [q 16][kv 64]

  const int bid = blockIdx.x;
  const int qt = 15 - (bid >> 6);     // descending: long blocks launch first
  const int bh = bid & 63, b = bh >> 4, h = bh & 15;
  const int q0 = qt * 128;
  const int tid = threadIdx.x, wid = tid >> 6, lane = tid & 63;
  const int quad = lane >> 4, l15 = lane & 15;
  const int wq = wid * 32;
  const u16* qkvb = qkv + (size_t)b * T * LD;
  const u16* vtb = vt + (size_t)b * 64 * 2048;
  const int sr0 = tid >> 3, sc0 = (tid & 7) * 8;
  const int sr1 = sr0 + 32;
  const float c1 = 0.18033688f;  // 0.125 * log2(e)
  const float M = 18.0f;         // fixed softmax shift
  short8 ones;
#pragma unroll
  for (int j = 0; j < 8; ++j) ones[j] = (short)0x3F80;  // bf16 1.0

  short8 qreg[2][2];
#pragma unroll
  for (int jt = 0; jt < 2; ++jt)
#pragma unroll
    for (int ks = 0; ks < 2; ++ks)
      qreg[jt][ks] = *(const short8*)(qkvb + (size_t)(q0 + wq + 16 * jt + l15) * LD + h * 64 + ks * 32 + quad * 8);

  f32x4 acc[4][2] = {};
  f32x4 accs[2] = {};   // row-sums via ones-MFMA

  short8 kr0 = *(const short8*)(qkvb + (size_t)sr0 * LD + 1024 + sc0);
  short8 kr1 = *(const short8*)(qkvb + (size_t)sr1 * LD + 1024 + sc0);
  short8 vr0 = *(const short8*)(vtb + (size_t)sr0 * 2048 + sc0);
  short8 vr1 = *(const short8*)(vtb + (size_t)sr1 * 2048 + sc0);

  const int ktmax = 2 * qt + 2;
  for (int kt = 0; kt < ktmax; ++kt) {
    const int kv0 = kt * 64;
    __syncthreads();
    *(short8*)&Ks[sr0 * 68 + sc0] = kr0;
    *(short8*)&Ks[sr1 * 68 + sc0] = kr1;
    *(short8*)&Vts[sr0 * 68 + sc0] = vr0;
    *(short8*)&Vts[sr1 * 68 + sc0] = vr1;
    __syncthreads();
    if (kt + 1 < ktmax) {
      const int nv0 = kv0 + 64;
      kr0 = *(const short8*)(qkvb + (size_t)(nv0 + sr0) * LD + 1024 + sc0);
      kr1 = *(const short8*)(qkvb + (size_t)(nv0 + sr1) * LD + 1024 + sc0);
      vr0 = *(const short8*)(vtb + (size_t)sr0 * 2048 + nv0 + sc0);
      vr1 = *(const short8*)(vtb + (size_t)sr1 * 2048 + nv0 + sc0);
    }
    if (kv0 > q0 + wq + 31) continue;  // fully masked for this wave

    // S^T = K * Q^T (kf shared across jt)
    f32x4 st[4][2] = {};
#pragma unroll
    for (int ks = 0; ks < 2; ++ks) {
      short8 kf[4];
#pragma unroll
      for (int i = 0; i < 4; ++i) kf[i] = *(const short8*)&Ks[(16 * i + l15) * 68 + ks * 32 + quad * 8];
#pragma unroll
      for (int i = 0; i < 4; ++i)
#pragma unroll
        for (int jt = 0; jt < 2; ++jt)
          st[i][jt] = mfma16(kf[i], qreg[jt][ks], st[i][jt]);
    }

    // fixed-shift softmax -> both jt P^T tiles written before any Pw read
    const bool needMask = (kv0 + 63 > q0 + wq);
#pragma unroll
    for (int jt = 0; jt < 2; ++jt) {
      u16* pw = &Pw[wid][jt][0];
      const int qg = q0 + wq + 16 * jt + l15;
#pragma unroll
      for (int i = 0; i < 4; ++i) {
        u16x4 pk;
#pragma unroll
        for (int r = 0; r < 4; ++r) {
          float p = __builtin_amdgcn_exp2f(fmaf(st[i][jt][r], c1, -M));
          if (needMask && (kv0 + 16 * i + quad * 4 + r > qg)) p = 0.f;
          pk[r] = f2bf_rna(p);
        }
        *(u16x4*)&pw[l15 * 68 + 16 * i + quad * 4] = pk;
      }
    }

    // O^T += V^T * P^T ; row-sum += ones * P^T (Vts frags shared across jt)
#pragma unroll
    for (int ks = 0; ks < 2; ++ks) {
      short8 pf[2];
#pragma unroll
      for (int jt = 0; jt < 2; ++jt)
        pf[jt] = *(const short8*)&Pw[wid][jt][l15 * 68 + ks * 32 + quad * 8];
#pragma unroll
      for (int id = 0; id < 4; ++id) {
        short8 vf = *(const short8*)&Vts[(16 * id + l15) * 68 + ks * 32 + quad * 8];
        acc[id][0] = mfma16(vf, pf[0], acc[id][0]);
        acc[id][1] = mfma16(vf, pf[1], acc[id][1]);
      }
      accs[0] = mfma16(ones, pf[0], accs[0]);
      accs[1] = mfma16(ones, pf[1], accs[1]);
    }
  }

  // epilogue: every element of accs[jt] equals this q-col's row-sum
#pragma unroll
  for (int jt = 0; jt < 2; ++jt) {
    const float inv = 1.f / accs[jt][0];
    const int qg = q0 + wq + 16 * jt + l15;
#pragma unroll
    for (int id = 0; id < 4; ++id) {
      u16x4 o;
#pragma unroll
      for (int r = 0; r < 4; ++r) o[r] = f2bf(acc[id][jt][r] * inv);
      *(u16x4*)(y + (size_t)(b * T + qg) * 1024 + h * 64 + 16 * id + quad * 4) = o;
    }
  }
}

extern "C" void kernel_launch(void* const* d_in, const int* in_sizes, int n_in,
                              void* d_out, int out_size, void* d_ws, size_t ws_size,
                              hipStream_t stream) {
  const float* x = (const float*)d_in[0];       // (4,2048,1024)
  const float* w_attn = (const float*)d_in[1];  // (1024,1152)
  const float* w_proj = (const float*)d_in[2];  // (1024,1024)
  float* out = (float*)d_out;                   // (4,2048,1024) fp32
  char* ws = (char*)d_ws;

  u16* wat = (u16*)ws;                       // 1152x1024 bf16
  u16* wpt = (u16*)(ws + 2359296);           // 1024x1024 bf16
  u16* xb  = (u16*)(ws + 4456448);           // 8192x1024 bf16
  u16* qkv = (u16*)(ws + 21233664);          // 8192x1152 bf16
  u16* vt  = (u16*)(ws + 40108032);          // 4x64x2048 bf16
  u16* y   = (u16*)(ws + 41156608);          // 8192x1024 bf16

  prep<<<dim3(4224), dim3(256), 0, stream>>>(x, w_attn, w_proj, xb, wat, wpt);
  gemm_bt<false, true><<<dim3(64, 9), 256, 0, stream>>>(xb, wat, qkv, vt, 1024, 1024, 1152, 1024);
  attn_kernel<<<dim3(1024), dim3(256), 0, stream>>>(qkv, vt, y);
  gemm_bt<true, false><<<dim3(64, 8), 256, 0, stream>>>(y, wpt, out, nullptr, 1024, 1024, 1024, 1024);
}